// Round 2
// baseline (108.833 us; speedup 1.0000x reference)
//
#include <hip/hip_runtime.h>
#include <hip/hip_bf16.h>

#define NCHAN 30

// FILTERS baked as per-channel 6-bit masks: bit g = FILTERS[g][c]
__constant__ int FMASK_C[NCHAN] = {63,63,33,33,21,5,33,33,5,5,33,33,5,5,9,9,
                                   11,11,11,11,11,11,0,0,2,2,10,10,63,63};

typedef float f32x4 __attribute__((ext_vector_type(4)));

__global__ __launch_bounds__(256) void ext_kernel(
    const float* __restrict__ tpl,
    const float* __restrict__ cons,
    const float* __restrict__ w_gas,
    const float* __restrict__ W1, const float* __restrict__ b1,
    const float* __restrict__ W2, const float* __restrict__ b2,
    const float* __restrict__ W3, const float* __restrict__ b3,
    const float* __restrict__ Wo, const float* __restrict__ bo,
    f32x4* __restrict__ out4)
{
    __shared__ float s_lds[256][8];     // 6 used, row padded to 32 B
    __shared__ float cons_lds[256][8];
    __shared__ float ewg_lds[8][32];    // ewg[k][c]: bank = c -> conflict-free / broadcast
    __shared__ int   mask_lds[32];

    const int tid = threadIdx.x;
    const int n   = blockIdx.x * 256 + tid;

    // ---- stage exp(w_gas) (240 values, (8,30) row-major) and filter masks ----
    if (tid < 8 * NCHAN) {
        int k = tid / NCHAN, c = tid - k * NCHAN;
        ewg_lds[k][c] = __expf(w_gas[tid]);
    }
    if (tid < NCHAN) mask_lds[tid] = FMASK_C[tid];

    // ---- stage cons[n][0..7] ----
    const float4* c4 = (const float4*)cons;
    float4 ca = c4[(size_t)n * 2];
    float4 cb = c4[(size_t)n * 2 + 1];
    *(float4*)&cons_lds[tid][0] = ca;
    *(float4*)&cons_lds[tid][4] = cb;

    // ---- per-row MLP: t_p(2) -> 6 -> 4 -> 4 -> sigmoid, for 6 groups ----
    float t0 = tpl[(size_t)n * 3 + 0];
    float t1 = tpl[(size_t)n * 3 + 1];
    #pragma unroll
    for (int g = 0; g < 6; ++g) {
        float h1[6], h2[4], h3[4];
        #pragma unroll
        for (int j = 0; j < 6; ++j)
            h1[j] = fmaxf(0.f, fmaf(W1[g*12 + j*2], t0,
                           fmaf(W1[g*12 + j*2 + 1], t1, b1[g*6 + j])));
        #pragma unroll
        for (int o = 0; o < 4; ++o) {
            float a = b2[g*4 + o];
            #pragma unroll
            for (int j = 0; j < 6; ++j) a = fmaf(W2[g*24 + o*6 + j], h1[j], a);
            h2[o] = fmaxf(0.f, a);
        }
        #pragma unroll
        for (int p = 0; p < 4; ++p) {
            float a = b3[g*4 + p];
            #pragma unroll
            for (int o = 0; o < 4; ++o) a = fmaf(W3[g*16 + p*4 + o], h2[o], a);
            h3[p] = fmaxf(0.f, a);
        }
        float a = bo[g];
        #pragma unroll
        for (int p = 0; p < 4; ++p) a = fmaf(Wo[g*4 + p], h3[p], a);
        s_lds[tid][g] = __fdividef(1.f, 1.f + __expf(-a));
    }

    __syncthreads();

    // ---- emit float32: each thread writes 60 float4 chunks (16 B, coalesced) ----
    // per block: 256 rows * 30 ch * 8 f32 = 15360 float4
    const size_t gbase = (size_t)blockIdx.x * (256 * NCHAN * 2);
    #pragma unroll 4
    for (int i = 0; i < 60; ++i) {
        const unsigned ch  = (unsigned)(i * 256 + tid);   // float4 index in block
        const unsigned nl  = ch / 60u;                    // local row
        const unsigned rem = ch - nl * 60u;
        const unsigned c   = rem >> 1;                    // channel
        const unsigned hi  = rem & 1u;                    // which half of the 8
        const int m = mask_lds[c];

        const float g0 = (m & 1)  ? s_lds[nl][0] : 0.f;
        const float g1 = (m & 2)  ? s_lds[nl][1] : 0.f;
        const float g2 = (m & 4)  ? s_lds[nl][2] : 0.f;
        const float g3 = (m & 8)  ? s_lds[nl][3] : 0.f;
        const float g4 = (m & 16) ? s_lds[nl][4] : 0.f;
        const float g5 = (m & 32) ? s_lds[nl][5] : 0.f;

        const float o0 = cons_lds[nl][0] * ewg_lds[0][c];
        const float o1 = cons_lds[nl][1] * ewg_lds[1][c];
        const float o2 = cons_lds[nl][2] * ewg_lds[2][c] * g0;
        const float o3 = cons_lds[nl][3] * ewg_lds[3][c] * g1;
        const float o4 = cons_lds[nl][4] * ewg_lds[4][c] * g2;
        const float o5 = cons_lds[nl][5] * ewg_lds[5][c] * g3;
        const float o6 = cons_lds[nl][6] * ewg_lds[6][c] * g4;
        const float o7 = cons_lds[nl][7] * ewg_lds[7][c] * g5;

        f32x4 v;
        v.x = hi ? o4 : o0;
        v.y = hi ? o5 : o1;
        v.z = hi ? o6 : o2;
        v.w = hi ? o7 : o3;
        __builtin_nontemporal_store(v, &out4[gbase + ch]);
    }
}

extern "C" void kernel_launch(void* const* d_in, const int* in_sizes, int n_in,
                              void* d_out, int out_size, void* d_ws, size_t ws_size,
                              hipStream_t stream) {
    const float* tpl  = (const float*)d_in[0];
    const float* cons = (const float*)d_in[1];
    const float* wgas = (const float*)d_in[2];
    const float* W1   = (const float*)d_in[3];
    const float* b1   = (const float*)d_in[4];
    const float* W2   = (const float*)d_in[5];
    const float* b2   = (const float*)d_in[6];
    const float* W3   = (const float*)d_in[7];
    const float* b3   = (const float*)d_in[8];
    const float* Wo   = (const float*)d_in[9];
    const float* bo   = (const float*)d_in[10];

    const int nrows = in_sizes[0] / 3;          // 524288
    const int blocks = nrows / 256;             // 2048

    ext_kernel<<<dim3(blocks), dim3(256), 0, stream>>>(
        tpl, cons, wgas, W1, b1, W2, b2, W3, b3, Wo, bo, (f32x4*)d_out);
}

// Round 3
// 105.434 us; speedup vs baseline: 1.0322x; 1.0322x over previous
//
#include <hip/hip_runtime.h>
#include <hip/hip_bf16.h>

#define NCHAN 30

// FILTERS baked as per-channel 6-bit masks: bit g = FILTERS[g][c]
__constant__ int FMASK_C[NCHAN] = {63,63,33,33,21,5,33,33,5,5,33,33,5,5,9,9,
                                   11,11,11,11,11,11,0,0,2,2,10,10,63,63};

typedef float f32x4 __attribute__((ext_vector_type(4)));

__global__ __launch_bounds__(256) void ext_kernel(
    const float* __restrict__ tpl,
    const float* __restrict__ cons,
    const float* __restrict__ w_gas,
    const float* __restrict__ W1, const float* __restrict__ b1,
    const float* __restrict__ W2, const float* __restrict__ b2,
    const float* __restrict__ W3, const float* __restrict__ b3,
    const float* __restrict__ Wo, const float* __restrict__ bo,
    f32x4* __restrict__ out4)
{
    // p_lds[n][k] = cons[n][k] * (k<2 ? 1 : s[n][k-2])   (row 32 B aligned)
    // E_lds[c][k] = (FILTERS[k-2][c] or k<2) ? exp(w_gas[k][c]) : 0
    __shared__ float p_lds[256][8];
    __shared__ float E_lds[32][8];

    const int tid = threadIdx.x;
    const int n   = blockIdx.x * 256 + tid;

    // ---- stage masked exp(w_gas): E[c][k], 240 values ----
    if (tid < 8 * NCHAN) {
        const int c = tid >> 3, k = tid & 7;          // [c][k] layout
        float e = __expf(w_gas[k * NCHAN + c]);       // w_gas is (8, 30) row-major
        if (k >= 2 && !((FMASK_C[c] >> (k - 2)) & 1)) e = 0.f;
        E_lds[c][k] = e;
    }

    // ---- per-row MLP: t_p(2) -> 6 -> 4 -> 4 -> sigmoid, for 6 groups ----
    const float4* c4 = (const float4*)cons;
    const float4 ca = c4[(size_t)n * 2];
    const float4 cb = c4[(size_t)n * 2 + 1];
    const float t0 = tpl[(size_t)n * 3 + 0];
    const float t1 = tpl[(size_t)n * 3 + 1];

    float s[6];
    #pragma unroll
    for (int g = 0; g < 6; ++g) {
        float h1[6], h2[4], h3[4];
        #pragma unroll
        for (int j = 0; j < 6; ++j)
            h1[j] = fmaxf(0.f, fmaf(W1[g*12 + j*2], t0,
                           fmaf(W1[g*12 + j*2 + 1], t1, b1[g*6 + j])));
        #pragma unroll
        for (int o = 0; o < 4; ++o) {
            float a = b2[g*4 + o];
            #pragma unroll
            for (int j = 0; j < 6; ++j) a = fmaf(W2[g*24 + o*6 + j], h1[j], a);
            h2[o] = fmaxf(0.f, a);
        }
        #pragma unroll
        for (int p = 0; p < 4; ++p) {
            float a = b3[g*4 + p];
            #pragma unroll
            for (int o = 0; o < 4; ++o) a = fmaf(W3[g*16 + p*4 + o], h2[o], a);
            h3[p] = fmaxf(0.f, a);
        }
        float a = bo[g];
        #pragma unroll
        for (int p = 0; p < 4; ++p) a = fmaf(Wo[g*4 + p], h3[p], a);
        s[g] = __fdividef(1.f, 1.f + __expf(-a));
    }

    // fold gates into cons -> p row (two aligned float4 writes)
    float4 pa, pb;
    pa.x = ca.x;        pa.y = ca.y;
    pa.z = ca.z * s[0]; pa.w = ca.w * s[1];
    pb.x = cb.x * s[2]; pb.y = cb.y * s[3];
    pb.z = cb.z * s[4]; pb.w = cb.w * s[5];
    *(float4*)&p_lds[tid][0] = pa;
    *(float4*)&p_lds[tid][4] = pb;

    __syncthreads();

    // ---- emit: per float4 chunk: 2x ds_read_b128 + 4 mul + 1 store ----
    // per block: 256 rows * 30 ch * 2 halves = 15360 float4
    const size_t gbase = (size_t)blockIdx.x * (256 * NCHAN * 2);
    #pragma unroll 6
    for (int i = 0; i < 60; ++i) {
        const unsigned ch  = (unsigned)(i * 256 + tid);   // float4 index in block
        const unsigned nl  = ch / 60u;                    // local row (magic-mul)
        const unsigned rem = ch - nl * 60u;
        const unsigned c   = rem >> 1;                    // channel
        const unsigned hi4 = (rem & 1u) << 2;             // 0 or 4

        const float4 pv = *(const float4*)&p_lds[nl][hi4];
        const float4 ev = *(const float4*)&E_lds[c][hi4];

        f32x4 v;
        v.x = pv.x * ev.x;
        v.y = pv.y * ev.y;
        v.z = pv.z * ev.z;
        v.w = pv.w * ev.w;
        __builtin_nontemporal_store(v, &out4[gbase + ch]);
    }
}

extern "C" void kernel_launch(void* const* d_in, const int* in_sizes, int n_in,
                              void* d_out, int out_size, void* d_ws, size_t ws_size,
                              hipStream_t stream) {
    const float* tpl  = (const float*)d_in[0];
    const float* cons = (const float*)d_in[1];
    const float* wgas = (const float*)d_in[2];
    const float* W1   = (const float*)d_in[3];
    const float* b1   = (const float*)d_in[4];
    const float* W2   = (const float*)d_in[5];
    const float* b2   = (const float*)d_in[6];
    const float* W3   = (const float*)d_in[7];
    const float* b3   = (const float*)d_in[8];
    const float* Wo   = (const float*)d_in[9];
    const float* bo   = (const float*)d_in[10];

    const int nrows = in_sizes[0] / 3;          // 524288
    const int blocks = nrows / 256;             // 2048

    ext_kernel<<<dim3(blocks), dim3(256), 0, stream>>>(
        tpl, cons, wgas, W1, b1, W2, b2, W3, b3, Wo, bo, (f32x4*)d_out);
}